// Round 2
// baseline (400.997 us; speedup 1.0000x reference)
//
#include <hip/hip_runtime.h>
#include <math.h>

// Problem constants
#define BB 4
#define CH 32
#define HH 96
#define WW 96
#define LL (HH*WW)          // 9216 tokens per image
#define DI 64               // inner dim
#define NS 16               // state dim
#define BL (BB*LL)          // 36864 total tokens
#define NCH 128             // scan chunks per sequence
#define CLEN (LL/NCH)       // 72 steps per chunk

__device__ __forceinline__ float sigmoidf_(float x){ return 1.f/(1.f+__expf(-x)); }
__device__ __forceinline__ float siluf_(float x){ return x*sigmoidf_(x); }
__device__ __forceinline__ float softplusf_(float x){
  return (x > 15.f) ? x : __logf(1.f + __expf(x));
}

// ---------------------------------------------------------------- K1: dilated depthwise 7x7 conv (pad=9, dil=3)
__global__ __launch_bounds__(256) void k1_conv_att(
    const float* __restrict__ x, const float* __restrict__ w,
    const float* __restrict__ bias, float* __restrict__ xa){
  int idx = blockIdx.x*256 + threadIdx.x;
  if (idx >= BB*CH*LL) return;
  int w0 = idx % WW; int h0 = (idx/WW) % HH; int c = (idx/LL) % CH;
  const float* xp = x + (idx/LL)*LL;   // (b,c) plane
  const float* wp = w + c*49;
  float acc = bias[c];
  #pragma unroll
  for (int kh=0; kh<7; ++kh){
    int hh = h0 + 3*kh - 9;
    if ((unsigned)hh >= HH) continue;
    const float* row = xp + hh*WW;
    #pragma unroll
    for (int kw=0; kw<7; ++kw){
      int ww = w0 + 3*kw - 9;
      if ((unsigned)ww < WW) acc += row[ww]*wp[kh*7+kw];
    }
  }
  xa[idx] = acc;   // (B,C,L)
}

// ---------------------------------------------------------------- K2: LayerNorm + in_proj + split + silu(z)
// block: 128 threads (lane j = output channel), 64 tokens per block
__global__ __launch_bounds__(128) void k2_ln_inproj(
    const float* __restrict__ xa, const float* __restrict__ w_in,
    const float* __restrict__ ln_w, const float* __restrict__ ln_b,
    float* __restrict__ xin, float* __restrict__ zs){
  __shared__ float xs[CH*65];      // [c][tok] padded
  __shared__ float wl[128*33];     // ln_w-folded weights, padded
  __shared__ float smu[64], srs[64];
  int tid = threadIdx.x;
  int tg0 = blockIdx.x*64;
  int bb = tg0 / LL;
  int l0 = tg0 % LL;
  const float* xab = xa + bb*CH*LL + l0;
  for (int r=0; r<16; ++r){
    int idx = r*128 + tid;
    int c = idx >> 6, t = idx & 63;
    xs[c*65+t] = xab[c*LL + t];
  }
  for (int r=0; r<32; ++r){
    int idx = r*128 + tid;          // 4096 = 128x32
    int j = idx >> 5, c = idx & 31;
    wl[j*33+c] = ln_w[c]*w_in[idx];
  }
  __syncthreads();
  if (tid < 64){
    float s=0.f, s2=0.f;
    #pragma unroll
    for (int c=0;c<CH;++c){ float v = xs[c*65+tid]; s+=v; s2+=v*v; }
    float mu = s*(1.f/CH);
    float var = s2*(1.f/CH) - mu*mu;
    smu[tid]=mu; srs[tid]=rsqrtf(var+1e-5f);
  }
  int j = tid;
  float swl=0.f, bj=0.f;
  #pragma unroll
  for (int c=0;c<CH;++c){ swl += wl[j*33+c]; bj += ln_b[c]*w_in[j*32+c]; }
  __syncthreads();
  for (int t=0;t<64;++t){
    float acc=0.f;
    #pragma unroll
    for (int c=0;c<CH;++c) acc += xs[c*65+t]*wl[j*33+c];
    float out = srs[t]*(acc - smu[t]*swl) + bj;
    int base = ((bb*LL) + l0 + t)*DI;
    if (j < DI) xin[base + j] = out;
    else        zs[base + (j-DI)] = siluf_(out);
  }
}

// ---------------------------------------------------------------- K3: causal conv1d + silu + x_proj + softplus(delta)
// block: 64 threads (lane = d), 64 tokens per block; dir in blockIdx.y (backward stored in flipped coords)
__global__ __launch_bounds__(64) void k3_conv1d_xproj(
    const float* __restrict__ xin,
    const float* __restrict__ cw_f, const float* __restrict__ cb_f,
    const float* __restrict__ wx_f, const float* __restrict__ wdt_f, const float* __restrict__ bdt_f,
    const float* __restrict__ cw_b, const float* __restrict__ cb_b,
    const float* __restrict__ wx_b, const float* __restrict__ wdt_b, const float* __restrict__ bdt_b,
    float* __restrict__ xc_f, float* __restrict__ dl_f, float* __restrict__ Bc_f, float* __restrict__ Cc_f,
    float* __restrict__ xc_b, float* __restrict__ dl_b, float* __restrict__ Bc_b, float* __restrict__ Cc_b){
  int d = threadIdx.x;
  int dir = blockIdx.y;
  int bb = blockIdx.z;
  int p0 = blockIdx.x*64;
  const float* cw  = dir? cw_b : cw_f;
  const float* cb  = dir? cb_b : cb_f;
  const float* wx  = dir? wx_b : wx_f;
  const float* wdt = dir? wdt_b : wdt_f;
  const float* bdt = dir? bdt_b : bdt_f;
  float* xcbuf = dir? xc_b : xc_f;
  float* dlbuf = dir? dl_b : dl_f;
  float* Bcb   = dir? Bc_b : Bc_f;
  float* Ccb   = dir? Cc_b : Cc_f;
  __shared__ float wxl[34*65];
  __shared__ float xcs[64];
  __shared__ float dtb[2];
  for (int idx=d; idx<34*64; idx+=64) wxl[(idx>>6)*65 + (idx&63)] = wx[idx];
  float c0=cw[d*4+0], c1=cw[d*4+1], c2=cw[d*4+2], c3=cw[d*4+3], cbv=cb[d];
  float wd0=wdt[d*2], wd1=wdt[d*2+1], bd=bdt[d];
  float u1=0.f,u2=0.f,u3=0.f;           // history: pos-1, pos-2, pos-3
  #pragma unroll
  for (int k=1;k<=3;++k){
    int pos = p0 - k;
    float v = 0.f;
    if (pos >= 0){ int ls = dir? (LL-1-pos) : pos; v = xin[(bb*LL+ls)*DI + d]; }
    if(k==1) u1=v; else if(k==2) u2=v; else u3=v;
  }
  __syncthreads();
  for (int t=0;t<64;++t){
    int pos = p0 + t;
    int ls = dir? (LL-1-pos) : pos;
    float u0 = xin[(bb*LL+ls)*DI + d];
    float xc = siluf_(cbv + c0*u3 + c1*u2 + c2*u1 + c3*u0);
    u3=u2; u2=u1; u1=u0;
    int tb = bb*LL+pos;
    xcbuf[tb*DI + d] = xc;
    xcs[d] = xc;
    __syncthreads();
    if (d < 34){
      float acc=0.f;
      #pragma unroll
      for (int c=0;c<DI;++c) acc += xcs[c]*wxl[d*65+c];
      if (d<2)       dtb[d] = acc;
      else if (d<18) Bcb[tb*NS + d-2]  = acc;
      else           Ccb[tb*NS + d-18] = acc;
    }
    __syncthreads();
    float dv = dtb[0]*wd0 + dtb[1]*wd1 + bd;
    dlbuf[tb*DI + d] = softplusf_(dv);
  }
}

// ---------------------------------------------------------------- P1: per-chunk local scan aggregates (P = prod dA, S = local state)
__global__ __launch_bounds__(64) void p1_scan_local(
    const float* __restrict__ dl_f, const float* __restrict__ xc_f, const float* __restrict__ Bc_f,
    const float* __restrict__ dl_b, const float* __restrict__ xc_b, const float* __restrict__ Bc_b,
    const float* __restrict__ Al_f, const float* __restrict__ Al_b,
    float* __restrict__ aggP, float* __restrict__ aggS){
  int d = threadIdx.x; int dir = blockIdx.y; int bb = blockIdx.z; int ch = blockIdx.x;
  const float* dl = dir? dl_b : dl_f;
  const float* xc = dir? xc_b : xc_f;
  const float* Bc = dir? Bc_b : Bc_f;
  const float* Al = dir? Al_b : Al_f;
  float A[NS];
  #pragma unroll
  for (int n=0;n<NS;++n) A[n] = -__expf(Al[d*NS+n]);
  float P[NS], S[NS];
  #pragma unroll
  for (int n=0;n<NS;++n){ P[n]=1.f; S[n]=0.f; }
  int p0 = ch*CLEN;
  for (int t=0;t<CLEN;++t){
    int tb = bb*LL + p0 + t;
    float dlt = dl[tb*DI+d];
    float xcv = xc[tb*DI+d];
    float dx = dlt*xcv;
    #pragma unroll
    for (int n=0;n<NS;++n){
      float Bn = Bc[tb*NS+n];
      float dA = __expf(dlt*A[n]);
      P[n] *= dA;
      S[n] = dA*S[n] + dx*Bn;
    }
  }
  int bdd = (bb*2+dir)*DI + d;
  float* pp = aggP + (bdd*NCH + ch)*NS;
  float* sp = aggS + (bdd*NCH + ch)*NS;
  #pragma unroll
  for (int n=0;n<NS;++n){ pp[n]=P[n]; sp[n]=S[n]; }
}

// ---------------------------------------------------------------- P2: scan over chunk aggregates -> incoming state per chunk
__global__ __launch_bounds__(256) void p2_scan_agg(
    const float* __restrict__ aggP, const float* __restrict__ aggS, float* __restrict__ hin){
  int t = blockIdx.x*256 + threadIdx.x; // 8192 chains
  if (t >= BB*2*DI*NS) return;
  int bdd = t >> 4, n = t & 15;
  float h = 0.f;
  for (int k=0;k<NCH;++k){
    int i = (bdd*NCH + k)*NS + n;
    hin[i] = h;
    h = aggP[i]*h + aggS[i];
  }
}

// ---------------------------------------------------------------- P3: re-run chunks with incoming state, emit y
__global__ __launch_bounds__(64) void p3_scan_out(
    const float* __restrict__ dl_f, const float* __restrict__ xc_f,
    const float* __restrict__ Bc_f, const float* __restrict__ Cc_f,
    const float* __restrict__ dl_b, const float* __restrict__ xc_b,
    const float* __restrict__ Bc_b, const float* __restrict__ Cc_b,
    const float* __restrict__ Al_f, const float* __restrict__ D_f,
    const float* __restrict__ Al_b, const float* __restrict__ D_b,
    const float* __restrict__ hin, float* __restrict__ y_f, float* __restrict__ y_b){
  int d = threadIdx.x; int dir = blockIdx.y; int bb = blockIdx.z; int ch = blockIdx.x;
  const float* dl = dir? dl_b : dl_f;
  const float* xc = dir? xc_b : xc_f;
  const float* Bc = dir? Bc_b : Bc_f;
  const float* Cc = dir? Cc_b : Cc_f;
  const float* Al = dir? Al_b : Al_f;
  const float* Dv = dir? D_b : D_f;
  float* y = dir? y_b : y_f;
  float A[NS];
  #pragma unroll
  for (int n=0;n<NS;++n) A[n] = -__expf(Al[d*NS+n]);
  float Dd = Dv[d];
  int bdd = (bb*2+dir)*DI + d;
  const float* hp = hin + (bdd*NCH + ch)*NS;
  float h[NS];
  #pragma unroll
  for (int n=0;n<NS;++n) h[n] = hp[n];
  int p0 = ch*CLEN;
  for (int t=0;t<CLEN;++t){
    int tb = bb*LL + p0 + t;
    float dlt = dl[tb*DI+d];
    float xcv = xc[tb*DI+d];
    float dx = dlt*xcv;
    float acc = xcv*Dd;
    #pragma unroll
    for (int n=0;n<NS;++n){
      float Bn = Bc[tb*NS+n];
      float Cn = Cc[tb*NS+n];
      float dA = __expf(dlt*A[n]);
      h[n] = dA*h[n] + dx*Bn;
      acc += h[n]*Cn;
    }
    y[tb*DI + d] = acc;   // backward stays in flipped coords; K4 unflips
  }
}

// ---------------------------------------------------------------- K4: gate + out_proj + transpose -> att2 (B,C,L)
__global__ __launch_bounds__(256) void k4_outproj(
    const float* __restrict__ y_f, const float* __restrict__ y_b, const float* __restrict__ zs,
    const float* __restrict__ w_out, float* __restrict__ att2){
  __shared__ float gt[64*64];    // [tok][d]
  __shared__ float wol[32*65];   // [c][d] padded
  __shared__ float ot[32*65];    // [c][tok] padded
  int tid = threadIdx.x;
  int tg0 = blockIdx.x*64;
  int bb = tg0/LL, l0 = tg0%LL;
  for (int r=0;r<8;++r){
    int idx = r*256+tid; // 2048
    wol[(idx>>6)*65 + (idx&63)] = w_out[idx];
  }
  for (int r=0;r<16;++r){
    int idx = r*256+tid;  // 4096
    int tk = idx>>6, d = idx&63;
    int l = l0+tk;
    int tbf = (bb*LL + l)*DI + d;
    int tbb = (bb*LL + (LL-1-l))*DI + d;
    gt[idx] = (y_f[tbf] + y_b[tbb]) * zs[tbf];
  }
  __syncthreads();
  int c = tid & 31, tsl = tid >> 5;
  for (int tg=0; tg<8; ++tg){
    int tk = tg*8+tsl;
    float acc=0.f;
    #pragma unroll
    for (int d=0;d<DI;++d) acc += gt[tk*64+d]*wol[c*65+d];
    ot[c*65+tk] = acc;
  }
  __syncthreads();
  float* a2 = att2 + bb*CH*LL + l0;
  for (int r=0;r<8;++r){
    int idx = r*256+tid;
    int cc2 = idx>>6, t = idx&63;
    a2[cc2*LL + t] = ot[cc2*65+t];
  }
}

// ---------------------------------------------------------------- K5a: channel mean/max pool over concat(x, att2)
__global__ __launch_bounds__(256) void k5a_pool(
    const float* __restrict__ x, const float* __restrict__ att2, float* __restrict__ pooled){
  int idx = blockIdx.x*256+threadIdx.x;
  if (idx>=BL) return;
  int bb = idx/LL, l = idx%LL;
  const float* xp = x + bb*CH*LL + l;
  const float* ap = att2 + bb*CH*LL + l;
  float s=0.f, m=-INFINITY;
  for (int c=0;c<CH;++c){
    float v1 = xp[c*LL], v2 = ap[c*LL];
    s += v1+v2;
    m = fmaxf(m, fmaxf(v1,v2));
  }
  pooled[(bb*2+0)*LL + l] = s*(1.f/64.f);
  pooled[(bb*2+1)*LL + l] = m;
}

// ---------------------------------------------------------------- K5b: 7x7 SE conv + sigmoid + combine
__global__ __launch_bounds__(256) void k5b_se_combine(
    const float* __restrict__ x, const float* __restrict__ att2,
    const float* __restrict__ pooled, const float* __restrict__ w_se,
    const float* __restrict__ b_se, float* __restrict__ outbuf){
  int idx = blockIdx.x*256+threadIdx.x;
  if (idx>=BL) return;
  int bb = idx/LL, l = idx%LL;
  int h0 = l/WW, w0 = l%WW;
  float a0 = b_se[0], a1 = b_se[1];
  #pragma unroll
  for (int i=0;i<2;++i){
    const float* pp = pooled + (bb*2+i)*LL;
    for (int kh=0;kh<7;++kh){
      int hh = h0+kh-3; if((unsigned)hh>=HH) continue;
      for (int kw=0;kw<7;++kw){
        int ww2 = w0+kw-3; if((unsigned)ww2>=WW) continue;
        float v = pp[hh*WW+ww2];
        a0 += v*w_se[(i*7+kh)*7+kw];
        a1 += v*w_se[((2+i)*7+kh)*7+kw];
      }
    }
  }
  float se0 = sigmoidf_(a0), se1 = sigmoidf_(a1);
  const float* xp = x + bb*CH*LL + l;
  const float* ap = att2 + bb*CH*LL + l;
  float* op = outbuf + bb*CH*LL + l;
  for (int c=0;c<CH;++c) op[c*LL] = xp[c*LL]*se0 + ap[c*LL]*se1;
}

// ---------------------------------------------------------------- K6: 3x3 conv 32->64 (pad=1), LDS row-banded
__global__ __launch_bounds__(256) void k6_conv3x3(
    const float* __restrict__ inb, const float* __restrict__ wc,
    const float* __restrict__ bc, float* __restrict__ out){
  __shared__ float lds[CH*3*98];
  int tid = threadIdx.x;
  int h = blockIdx.x, bb = blockIdx.y;
  const float* ib = inb + bb*CH*LL;
  for (int r=0; r<36; ++r){           // 36*256 = 9216 = 32ci*3rows*96w
    int idx = r*256+tid;
    int ci = idx/(3*96); int rr = (idx/96)%3; int ww2 = idx%96;
    int hh = h + rr - 1;
    float v = ((unsigned)hh < HH) ? ib[ci*LL + hh*WW + ww2] : 0.f;
    lds[(ci*3+rr)*98 + 1 + ww2] = v;
  }
  if (tid < 96){
    int ci = tid/3, rr = tid%3;
    lds[(ci*3+rr)*98 + 0]  = 0.f;
    lds[(ci*3+rr)*98 + 97] = 0.f;
  }
  __syncthreads();
  int coslot = tid >> 4, wslot = tid & 15;
  int co0 = coslot*4, wb = wslot*6;
  float acc[4][6];
  #pragma unroll
  for (int q=0;q<4;++q)
    #pragma unroll
    for (int j2=0;j2<6;++j2) acc[q][j2]=0.f;
  for (int ci=0; ci<CH; ++ci){
    float wt[4][9];
    #pragma unroll
    for (int q=0;q<4;++q){
      const float* wp = wc + ((co0+q)*CH + ci)*9;
      #pragma unroll
      for (int k=0;k<9;++k) wt[q][k] = wp[k];
    }
    #pragma unroll
    for (int kh=0;kh<3;++kh){
      const float* row = &lds[(ci*3+kh)*98 + wb];
      float s[8];
      #pragma unroll
      for (int t2=0;t2<8;++t2) s[t2] = row[t2];
      #pragma unroll
      for (int q=0;q<4;++q)
        #pragma unroll
        for (int kw=0;kw<3;++kw){
          float wv = wt[q][kh*3+kw];
          #pragma unroll
          for (int j2=0;j2<6;++j2) acc[q][j2] += s[j2+kw]*wv;
        }
    }
  }
  #pragma unroll
  for (int q=0;q<4;++q){
    int co = co0+q;
    float bv = bc[co];
    float* op = out + (bb*64 + co)*LL + h*WW + wb;
    #pragma unroll
    for (int j2=0;j2<6;++j2) op[j2] = acc[q][j2]+bv;
  }
}

// ---------------------------------------------------------------- launch
extern "C" void kernel_launch(void* const* d_in, const int* in_sizes, int n_in,
                              void* d_out, int out_size, void* d_ws, size_t ws_size,
                              hipStream_t stream){
  const float* x     = (const float*)d_in[0];
  const float* w_att = (const float*)d_in[1];
  const float* b_att = (const float*)d_in[2];
  const float* ln_w  = (const float*)d_in[3];
  const float* ln_b  = (const float*)d_in[4];
  const float* w_in  = (const float*)d_in[5];
  const float* cw_f  = (const float*)d_in[6];
  const float* cb_f  = (const float*)d_in[7];
  const float* wx_f  = (const float*)d_in[8];
  const float* wdt_f = (const float*)d_in[9];
  const float* bdt_f = (const float*)d_in[10];
  const float* Al_f  = (const float*)d_in[11];
  const float* D_f   = (const float*)d_in[12];
  const float* cw_b  = (const float*)d_in[13];
  const float* cb_b  = (const float*)d_in[14];
  const float* wx_b  = (const float*)d_in[15];
  const float* wdt_b = (const float*)d_in[16];
  const float* bdt_b = (const float*)d_in[17];
  const float* Al_b  = (const float*)d_in[18];
  const float* D_b   = (const float*)d_in[19];
  const float* w_out = (const float*)d_in[20];
  const float* w_se  = (const float*)d_in[21];
  const float* b_se  = (const float*)d_in[22];
  const float* w_conv= (const float*)d_in[23];
  const float* b_conv= (const float*)d_in[24];

  float* ws = (float*)d_ws;
  // region reuse: xa (dead after K2) <- att2 (K4+); xin (dead after K3) <- outbuf + pooled
  float* xa     = ws + 0;          // 1179648
  float* att2   = ws + 0;
  float* xin    = ws + 1179648;    // 2359296
  float* outbuf = ws + 1179648;    // 1179648 (after xin dead)
  float* pooled = ws + 2359296;    // 73728   (after xin dead)
  float* zs     = ws + 3538944;    // 2359296
  float* xc_f   = ws + 5898240;    // 2359296
  float* xc_b   = ws + 8257536;
  float* dl_f   = ws + 10616832;
  float* dl_b   = ws + 12976128;
  float* Bc_f   = ws + 15335424;   // 589824
  float* Bc_b   = ws + 15925248;
  float* Cc_f   = ws + 16515072;
  float* Cc_b   = ws + 17104896;
  float* y_f    = ws + 17694720;   // 2359296
  float* y_b    = ws + 20054016;
  float* aggP   = ws + 22413312;   // 1048576
  float* aggS   = ws + 23461888;   // 1048576
  float* hin    = ws + 24510464;   // 1048576  -> total 25559040 floats = 102.2 MB

  k1_conv_att<<<4608,256,0,stream>>>(x, w_att, b_att, xa);
  k2_ln_inproj<<<576,128,0,stream>>>(xa, w_in, ln_w, ln_b, xin, zs);
  k3_conv1d_xproj<<<dim3(144,2,BB),64,0,stream>>>(xin,
      cw_f,cb_f,wx_f,wdt_f,bdt_f, cw_b,cb_b,wx_b,wdt_b,bdt_b,
      xc_f,dl_f,Bc_f,Cc_f, xc_b,dl_b,Bc_b,Cc_b);
  p1_scan_local<<<dim3(NCH,2,BB),64,0,stream>>>(dl_f,xc_f,Bc_f, dl_b,xc_b,Bc_b, Al_f,Al_b, aggP,aggS);
  p2_scan_agg<<<32,256,0,stream>>>(aggP,aggS,hin);
  p3_scan_out<<<dim3(NCH,2,BB),64,0,stream>>>(dl_f,xc_f,Bc_f,Cc_f, dl_b,xc_b,Bc_b,Cc_b,
      Al_f,D_f, Al_b,D_b, hin, y_f,y_b);
  k4_outproj<<<576,256,0,stream>>>(y_f,y_b,zs,w_out,att2);
  k5a_pool<<<144,256,0,stream>>>(x, att2, pooled);
  k5b_se_combine<<<144,256,0,stream>>>(x, att2, pooled, w_se, b_se, outbuf);
  k6_conv3x3<<<dim3(HH,BB),256,0,stream>>>(outbuf, w_conv, b_conv, (float*)d_out);
}

// Round 4
// 367.501 us; speedup vs baseline: 1.0911x; 1.0911x over previous
//
#include <hip/hip_runtime.h>
#include <math.h>

// Problem constants
#define BB 4
#define CH 32
#define HH 96
#define WW 96
#define LL (HH*WW)          // 9216 tokens per image
#define DI 64               // inner dim
#define NS 16               // state dim
#define BL (BB*LL)          // 36864 total tokens
#define NCH 144             // scan chunks per sequence
#define CLEN (LL/NCH)       // 64 steps per chunk

__device__ __forceinline__ float sigmoidf_(float x){ return 1.f/(1.f+__expf(-x)); }
__device__ __forceinline__ float siluf_(float x){ return x*sigmoidf_(x); }
__device__ __forceinline__ float softplusf_(float x){
  return (x > 15.f) ? x : __logf(1.f + __expf(x));
}
// single-wave LDS fence: order ds_write -> ds_read within one wave without
// s_barrier (avoids the vmcnt(0) drain __syncthreads would impose)
#define WAVE_LDS_FENCE() do { asm volatile("s_waitcnt lgkmcnt(0)" ::: "memory"); __builtin_amdgcn_sched_barrier(0); } while(0)

// ---------------------------------------------------------------- K1: dilated depthwise 7x7 conv (pad=9, dil=3)
__global__ __launch_bounds__(256) void k1_conv_att(
    const float* __restrict__ x, const float* __restrict__ w,
    const float* __restrict__ bias, float* __restrict__ xa){
  int idx = blockIdx.x*256 + threadIdx.x;
  if (idx >= BB*CH*LL) return;
  int w0 = idx % WW; int h0 = (idx/WW) % HH; int c = (idx/LL) % CH;
  const float* xp = x + (idx/LL)*LL;   // (b,c) plane
  const float* wp = w + c*49;
  float acc = bias[c];
  #pragma unroll
  for (int kh=0; kh<7; ++kh){
    int hh = h0 + 3*kh - 9;
    if ((unsigned)hh >= HH) continue;
    const float* row = xp + hh*WW;
    #pragma unroll
    for (int kw=0; kw<7; ++kw){
      int ww = w0 + 3*kw - 9;
      if ((unsigned)ww < WW) acc += row[ww]*wp[kh*7+kw];
    }
  }
  xa[idx] = acc;   // (B,C,L)
}

// ---------------------------------------------------------------- K2: LayerNorm + in_proj + split + silu(z)
__global__ __launch_bounds__(128) void k2_ln_inproj(
    const float* __restrict__ xa, const float* __restrict__ w_in,
    const float* __restrict__ ln_w, const float* __restrict__ ln_b,
    float* __restrict__ xin, float* __restrict__ zs){
  __shared__ float xs[CH*65];      // [c][tok] padded
  __shared__ float wl[128*33];     // ln_w-folded weights, padded
  __shared__ float smu[64], srs[64];
  int tid = threadIdx.x;
  int tg0 = blockIdx.x*64;
  int bb = tg0 / LL;
  int l0 = tg0 % LL;
  const float* xab = xa + bb*CH*LL + l0;
  for (int r=0; r<16; ++r){
    int idx = r*128 + tid;
    int c = idx >> 6, t = idx & 63;
    xs[c*65+t] = xab[c*LL + t];
  }
  for (int r=0; r<32; ++r){
    int idx = r*128 + tid;          // 4096 = 128x32
    int j = idx >> 5, c = idx & 31;
    wl[j*33+c] = ln_w[c]*w_in[idx];
  }
  __syncthreads();
  if (tid < 64){
    float s=0.f, s2=0.f;
    #pragma unroll
    for (int c=0;c<CH;++c){ float v = xs[c*65+tid]; s+=v; s2+=v*v; }
    float mu = s*(1.f/CH);
    float var = s2*(1.f/CH) - mu*mu;
    smu[tid]=mu; srs[tid]=rsqrtf(var+1e-5f);
  }
  int j = tid;
  float swl=0.f, bj=0.f;
  #pragma unroll
  for (int c=0;c<CH;++c){ swl += wl[j*33+c]; bj += ln_b[c]*w_in[j*32+c]; }
  __syncthreads();
  for (int t=0;t<64;++t){
    float acc=0.f;
    #pragma unroll
    for (int c=0;c<CH;++c) acc += xs[c*65+t]*wl[j*33+c];
    float out = srs[t]*(acc - smu[t]*swl) + bj;
    int base = ((bb*LL) + l0 + t)*DI;
    if (j < DI) xin[base + j] = out;
    else        zs[base + (j-DI)] = siluf_(out);
  }
}

// ---------------------------------------------------------------- K3 fused: conv1d+silu + x_proj + softplus + local scan (old P1)
// 1 wave per block, 64 tokens (= one scan chunk). No s_barrier anywhere.
// Lane roles per token: d-role (conv, dl, scan state) and k-role (x_proj, k<34).
__global__ __launch_bounds__(64) void k3_fused(
    const float* __restrict__ xin,
    const float* __restrict__ cw_f, const float* __restrict__ cb_f,
    const float* __restrict__ wx_f, const float* __restrict__ wdt_f, const float* __restrict__ bdt_f,
    const float* __restrict__ Al_f,
    const float* __restrict__ cw_b, const float* __restrict__ cb_b,
    const float* __restrict__ wx_b, const float* __restrict__ wdt_b, const float* __restrict__ bdt_b,
    const float* __restrict__ Al_b,
    float* __restrict__ xc_f, float* __restrict__ dl_f, float* __restrict__ Bc_f, float* __restrict__ Cc_f,
    float* __restrict__ xc_b, float* __restrict__ dl_b, float* __restrict__ Bc_b, float* __restrict__ Cc_b,
    float* __restrict__ aggP, float* __restrict__ aggS){
  int lane = threadIdx.x;
  int dir = blockIdx.y;
  int bb = blockIdx.z;
  int ch = blockIdx.x;
  int p0 = ch*CLEN;
  const float* cw  = dir? cw_b : cw_f;
  const float* cb  = dir? cb_b : cb_f;
  const float* wx  = dir? wx_b : wx_f;
  const float* wdt = dir? wdt_b : wdt_f;
  const float* bdt = dir? bdt_b : bdt_f;
  const float* Al  = dir? Al_b : Al_f;
  float* xcbuf = dir? xc_b : xc_f;
  float* dlbuf = dir? dl_b : dl_f;
  float* Bcb   = dir? Bc_b : Bc_f;
  float* Ccb   = dir? Cc_b : Cc_f;

  __shared__ float xcs[64];    // current token's xc vector
  __shared__ float bcs[16];    // current token's Bc
  __shared__ float dtb[2];     // current token's dt pre-activation

  // ---- per-lane constants
  int d = lane;
  float c0=cw[d*4+0], c1=cw[d*4+1], c2=cw[d*4+2], c3=cw[d*4+3], cbv=cb[d];
  float wd0=wdt[d*2], wd1=wdt[d*2+1], bd=bdt[d];
  float A[NS];
  #pragma unroll
  for (int n4=0;n4<4;++n4){
    float4 av = *(const float4*)&Al[d*NS + n4*4];
    A[n4*4+0] = -__expf(av.x); A[n4*4+1] = -__expf(av.y);
    A[n4*4+2] = -__expf(av.z); A[n4*4+3] = -__expf(av.w);
  }
  // x_proj weights in registers: lane k (<34) holds wx[k][0..63]
  float wreg[64];
  if (lane < 34){
    #pragma unroll
    for (int c4=0;c4<16;++c4){
      float4 wv = *(const float4*)&wx[lane*64 + c4*4];
      wreg[c4*4+0]=wv.x; wreg[c4*4+1]=wv.y; wreg[c4*4+2]=wv.z; wreg[c4*4+3]=wv.w;
    }
  }
  // scan state
  float P[NS], S[NS];
  #pragma unroll
  for (int n=0;n<NS;++n){ P[n]=1.f; S[n]=0.f; }
  // conv history
  float u1=0.f,u2=0.f,u3=0.f;
  #pragma unroll
  for (int k=1;k<=3;++k){
    int pos = p0 - k;
    float v = 0.f;
    if (pos >= 0){ int ls = dir? (LL-1-pos) : pos; v = xin[(bb*LL+ls)*DI + d]; }
    if(k==1) u1=v; else if(k==2) u2=v; else u3=v;
  }

  for (int t=0;t<CLEN;++t){
    int pos = p0 + t;
    int ls = dir? (LL-1-pos) : pos;
    int tb = bb*LL + pos;
    // phase A: conv1d + silu (lane = d)
    float u0 = xin[(bb*LL+ls)*DI + d];
    float xc = siluf_(cbv + c0*u3 + c1*u2 + c2*u1 + c3*u0);
    u3=u2; u2=u1; u1=u0;
    xcbuf[tb*DI + d] = xc;           // global (no barrier waits on this)
    xcs[d] = xc;                     // LDS row
    WAVE_LDS_FENCE();
    // phase B: x_proj (lane = k < 34), xc broadcast from LDS, weights in regs
    if (lane < 34){
      float acc = 0.f;
      #pragma unroll
      for (int c4=0;c4<16;++c4){
        float4 xv = *(const float4*)&xcs[c4*4];   // uniform broadcast
        acc += xv.x*wreg[c4*4+0] + xv.y*wreg[c4*4+1]
             + xv.z*wreg[c4*4+2] + xv.w*wreg[c4*4+3];
      }
      if (lane < 2){
        dtb[lane] = acc;
      } else if (lane < 18){
        Bcb[tb*NS + lane-2] = acc;
        bcs[lane-2] = acc;
      } else {
        Ccb[tb*NS + lane-18] = acc;
      }
    }
    WAVE_LDS_FENCE();
    // phase C: delta + dl write + local scan update (lane = d)
    float dt0 = dtb[0], dt1 = dtb[1];
    float dlt = softplusf_(dt0*wd0 + dt1*wd1 + bd);
    dlbuf[tb*DI + d] = dlt;
    float dx = dlt*xc;
    #pragma unroll
    for (int n4=0;n4<4;++n4){
      float4 bv = *(const float4*)&bcs[n4*4];     // uniform broadcast
      float bvv[4] = {bv.x,bv.y,bv.z,bv.w};
      #pragma unroll
      for (int j=0;j<4;++j){
        int n = n4*4+j;
        float dA = __expf(dlt*A[n]);
        P[n] *= dA;
        S[n] = dA*S[n] + dx*bvv[j];
      }
    }
  }
  // write chunk aggregates (old P1 output)
  int bdd = (bb*2+dir)*DI + d;
  float* pp = aggP + (bdd*NCH + ch)*NS;
  float* sp = aggS + (bdd*NCH + ch)*NS;
  #pragma unroll
  for (int n4=0;n4<4;++n4){
    *(float4*)&pp[n4*4] = make_float4(P[n4*4+0],P[n4*4+1],P[n4*4+2],P[n4*4+3]);
    *(float4*)&sp[n4*4] = make_float4(S[n4*4+0],S[n4*4+1],S[n4*4+2],S[n4*4+3]);
  }
}

// ---------------------------------------------------------------- P2: scan over chunk aggregates -> incoming state per chunk
// NOTE: hin may alias aggP (in-place); no __restrict__, read-before-write order.
__global__ __launch_bounds__(256) void p2_scan_agg(
    const float* aggP, const float* aggS, float* hin){
  int t = blockIdx.x*256 + threadIdx.x; // 8192 chains
  if (t >= BB*2*DI*NS) return;
  int bdd = t >> 4, n = t & 15;
  float h = 0.f;
  for (int k=0;k<NCH;++k){
    int i = (bdd*NCH + k)*NS + n;
    float pv = aggP[i], sv = aggS[i];
    hin[i] = h;
    h = pv*h + sv;
  }
}

// ---------------------------------------------------------------- P3: re-run chunks with incoming state, emit y
// lanes: 32 d-slots x 2 n-halves (8 states each); blockIdx.y = dir*2 + dhalf
__global__ __launch_bounds__(64) void p3_scan_out(
    const float* __restrict__ dl_f, const float* __restrict__ xc_f,
    const float* __restrict__ Bc_f, const float* __restrict__ Cc_f,
    const float* __restrict__ dl_b, const float* __restrict__ xc_b,
    const float* __restrict__ Bc_b, const float* __restrict__ Cc_b,
    const float* __restrict__ Al_f, const float* __restrict__ D_f,
    const float* __restrict__ Al_b, const float* __restrict__ D_b,
    const float* __restrict__ hin, float* __restrict__ y_f, float* __restrict__ y_b){
  int lane = threadIdx.x;
  int dir = blockIdx.y >> 1;
  int dhalf = blockIdx.y & 1;
  int bb = blockIdx.z; int ch = blockIdx.x;
  int d = dhalf*32 + (lane & 31);
  int nb = (lane >> 5) * 8;          // n-base: 0 or 8
  const float* dl = dir? dl_b : dl_f;
  const float* xc = dir? xc_b : xc_f;
  const float* Bc = dir? Bc_b : Bc_f;
  const float* Cc = dir? Cc_b : Cc_f;
  const float* Al = dir? Al_b : Al_f;
  const float* Dv = dir? D_b : D_f;
  float* y = dir? y_b : y_f;
  float A[8];
  #pragma unroll
  for (int n4=0;n4<2;++n4){
    float4 av = *(const float4*)&Al[d*NS + nb + n4*4];
    A[n4*4+0] = -__expf(av.x); A[n4*4+1] = -__expf(av.y);
    A[n4*4+2] = -__expf(av.z); A[n4*4+3] = -__expf(av.w);
  }
  float Dd = Dv[d];
  int bdd = (bb*2+dir)*DI + d;
  const float* hp = hin + (bdd*NCH + ch)*NS + nb;
  float h[8];
  #pragma unroll
  for (int n4=0;n4<2;++n4){
    float4 hv = *(const float4*)&hp[n4*4];
    h[n4*4+0]=hv.x; h[n4*4+1]=hv.y; h[n4*4+2]=hv.z; h[n4*4+3]=hv.w;
  }
  int p0 = ch*CLEN;
  for (int t=0;t<CLEN;++t){
    int tb = bb*LL + p0 + t;
    float dlt = dl[tb*DI+d];
    float xcv = xc[tb*DI+d];
    float dx = dlt*xcv;
    float acc = 0.f;
    #pragma unroll
    for (int n4=0;n4<2;++n4){
      float4 bv = *(const float4*)&Bc[tb*NS + nb + n4*4];
      float4 cv = *(const float4*)&Cc[tb*NS + nb + n4*4];
      float bvv[4]={bv.x,bv.y,bv.z,bv.w}, cvv[4]={cv.x,cv.y,cv.z,cv.w};
      #pragma unroll
      for (int j=0;j<4;++j){
        int n = n4*4+j;
        float dA = __expf(dlt*A[n]);
        h[n] = dA*h[n] + dx*bvv[j];
        acc += h[n]*cvv[j];
      }
    }
    float other = __shfl_xor(acc, 32, 64);
    if (lane < 32) y[tb*DI + d] = xcv*Dd + acc + other;
  }
}

// ---------------------------------------------------------------- K4: gate + out_proj + transpose -> att2 (B,C,L)
__global__ __launch_bounds__(256) void k4_outproj(
    const float* __restrict__ y_f, const float* __restrict__ y_b, const float* __restrict__ zs,
    const float* __restrict__ w_out, float* __restrict__ att2){
  __shared__ float gt[64*64];    // [tok][d]
  __shared__ float wol[32*65];   // [c][d] padded
  __shared__ float ot[32*65];    // [c][tok] padded
  int tid = threadIdx.x;
  int tg0 = blockIdx.x*64;
  int bb = tg0/LL, l0 = tg0%LL;
  for (int r=0;r<8;++r){
    int idx = r*256+tid; // 2048
    wol[(idx>>6)*65 + (idx&63)] = w_out[idx];
  }
  for (int r=0;r<16;++r){
    int idx = r*256+tid;  // 4096
    int tk = idx>>6, d = idx&63;
    int l = l0+tk;
    int tbf = (bb*LL + l)*DI + d;
    int tbb = (bb*LL + (LL-1-l))*DI + d;
    gt[idx] = (y_f[tbf] + y_b[tbb]) * zs[tbf];
  }
  __syncthreads();
  int c = tid & 31, tsl = tid >> 5;
  for (int tg=0; tg<8; ++tg){
    int tk = tg*8+tsl;
    float acc=0.f;
    #pragma unroll
    for (int d=0;d<DI;++d) acc += gt[tk*64+d]*wol[c*65+d];
    ot[c*65+tk] = acc;
  }
  __syncthreads();
  float* a2 = att2 + bb*CH*LL + l0;
  for (int r=0;r<8;++r){
    int idx = r*256+tid;
    int cc2 = idx>>6, t = idx&63;
    a2[cc2*LL + t] = ot[cc2*65+t];
  }
}

// ---------------------------------------------------------------- K5a: channel mean/max pool over concat(x, att2)
__global__ __launch_bounds__(256) void k5a_pool(
    const float* __restrict__ x, const float* __restrict__ att2, float* __restrict__ pooled){
  int idx = blockIdx.x*256+threadIdx.x;
  if (idx>=BL) return;
  int bb = idx/LL, l = idx%LL;
  const float* xp = x + bb*CH*LL + l;
  const float* ap = att2 + bb*CH*LL + l;
  float s=0.f, m=-INFINITY;
  for (int c=0;c<CH;++c){
    float v1 = xp[c*LL], v2 = ap[c*LL];
    s += v1+v2;
    m = fmaxf(m, fmaxf(v1,v2));
  }
  pooled[(bb*2+0)*LL + l] = s*(1.f/64.f);
  pooled[(bb*2+1)*LL + l] = m;
}

// ---------------------------------------------------------------- K5b: 7x7 SE conv + sigmoid + combine
__global__ __launch_bounds__(256) void k5b_se_combine(
    const float* __restrict__ x, const float* __restrict__ att2,
    const float* __restrict__ pooled, const float* __restrict__ w_se,
    const float* __restrict__ b_se, float* __restrict__ outbuf){
  int idx = blockIdx.x*256+threadIdx.x;
  if (idx>=BL) return;
  int bb = idx/LL, l = idx%LL;
  int h0 = l/WW, w0 = l%WW;
  float a0 = b_se[0], a1 = b_se[1];
  #pragma unroll
  for (int i=0;i<2;++i){
    const float* pp = pooled + (bb*2+i)*LL;
    for (int kh=0;kh<7;++kh){
      int hh = h0+kh-3; if((unsigned)hh>=HH) continue;
      for (int kw=0;kw<7;++kw){
        int ww2 = w0+kw-3; if((unsigned)ww2>=WW) continue;
        float v = pp[hh*WW+ww2];
        a0 += v*w_se[(i*7+kh)*7+kw];
        a1 += v*w_se[((2+i)*7+kh)*7+kw];
      }
    }
  }
  float se0 = sigmoidf_(a0), se1 = sigmoidf_(a1);
  const float* xp = x + bb*CH*LL + l;
  const float* ap = att2 + bb*CH*LL + l;
  float* op = outbuf + bb*CH*LL + l;
  for (int c=0;c<CH;++c) op[c*LL] = xp[c*LL]*se0 + ap[c*LL]*se1;
}

// ---------------------------------------------------------------- K6: 3x3 conv 32->64 (pad=1), LDS row-banded, co-split
__global__ __launch_bounds__(256) void k6_conv3x3(
    const float* __restrict__ inb, const float* __restrict__ wc,
    const float* __restrict__ bc, float* __restrict__ out){
  __shared__ float lds[CH*3*98];
  int tid = threadIdx.x;
  int h = blockIdx.x, cohalf = blockIdx.y, bb = blockIdx.z;
  const float* ib = inb + bb*CH*LL;
  for (int r=0; r<36; ++r){           // 36*256 = 9216 = 32ci*3rows*96w
    int idx = r*256+tid;
    int ci = idx/(3*96); int rr = (idx/96)%3; int ww2 = idx%96;
    int hh = h + rr - 1;
    float v = ((unsigned)hh < HH) ? ib[ci*LL + hh*WW + ww2] : 0.f;
    lds[(ci*3+rr)*98 + 1 + ww2] = v;
  }
  if (tid < 96){
    int ci = tid/3, rr = tid%3;
    lds[(ci*3+rr)*98 + 0]  = 0.f;
    lds[(ci*3+rr)*98 + 97] = 0.f;
  }
  __syncthreads();
  int coslot = tid >> 4, wslot = tid & 15;
  int co0 = cohalf*32 + coslot*2, wb = wslot*6;
  float acc[2][6];
  #pragma unroll
  for (int q=0;q<2;++q)
    #pragma unroll
    for (int j2=0;j2<6;++j2) acc[q][j2]=0.f;
  for (int ci=0; ci<CH; ++ci){
    float wt[2][9];
    #pragma unroll
    for (int q=0;q<2;++q){
      const float* wp = wc + ((co0+q)*CH + ci)*9;
      #pragma unroll
      for (int k=0;k<9;++k) wt[q][k] = wp[k];
    }
    #pragma unroll
    for (int kh=0;kh<3;++kh){
      const float* row = &lds[(ci*3+kh)*98 + wb];
      float s[8];
      #pragma unroll
      for (int t2=0;t2<8;++t2) s[t2] = row[t2];
      #pragma unroll
      for (int q=0;q<2;++q)
        #pragma unroll
        for (int kw=0;kw<3;++kw){
          float wv = wt[q][kh*3+kw];
          #pragma unroll
          for (int j2=0;j2<6;++j2) acc[q][j2] += s[j2+kw]*wv;
        }
    }
  }
  #pragma unroll
  for (int q=0;q<2;++q){
    int co = co0+q;
    float bv = bc[co];
    float* op = out + (bb*64 + co)*LL + h*WW + wb;
    #pragma unroll
    for (int j2=0;j2<6;++j2) op[j2] = acc[q][j2]+bv;
  }
}

// ---------------------------------------------------------------- launch
extern "C" void kernel_launch(void* const* d_in, const int* in_sizes, int n_in,
                              void* d_out, int out_size, void* d_ws, size_t ws_size,
                              hipStream_t stream){
  const float* x     = (const float*)d_in[0];
  const float* w_att = (const float*)d_in[1];
  const float* b_att = (const float*)d_in[2];
  const float* ln_w  = (const float*)d_in[3];
  const float* ln_b  = (const float*)d_in[4];
  const float* w_in  = (const float*)d_in[5];
  const float* cw_f  = (const float*)d_in[6];
  const float* cb_f  = (const float*)d_in[7];
  const float* wx_f  = (const float*)d_in[8];
  const float* wdt_f = (const float*)d_in[9];
  const float* bdt_f = (const float*)d_in[10];
  const float* Al_f  = (const float*)d_in[11];
  const float* D_f   = (const float*)d_in[12];
  const float* cw_b  = (const float*)d_in[13];
  const float* cb_b  = (const float*)d_in[14];
  const float* wx_b  = (const float*)d_in[15];
  const float* wdt_b = (const float*)d_in[16];
  const float* bdt_b = (const float*)d_in[17];
  const float* Al_b  = (const float*)d_in[18];
  const float* D_b   = (const float*)d_in[19];
  const float* w_out = (const float*)d_in[20];
  const float* w_se  = (const float*)d_in[21];
  const float* b_se  = (const float*)d_in[22];
  const float* w_conv= (const float*)d_in[23];
  const float* b_conv= (const float*)d_in[24];

  float* ws = (float*)d_ws;
  // region reuse: xa (dead after K2) <- att2 (K4+); xin (dead after K3) <- outbuf + pooled
  float* xa     = ws + 0;          // 1179648
  float* att2   = ws + 0;
  float* xin    = ws + 1179648;    // 2359296
  float* outbuf = ws + 1179648;    // 1179648 (after xin dead)
  float* pooled = ws + 2359296;    // 73728   (after xin dead)
  float* zs     = ws + 3538944;    // 2359296
  float* xc_f   = ws + 5898240;    // 2359296
  float* xc_b   = ws + 8257536;
  float* dl_f   = ws + 10616832;
  float* dl_b   = ws + 12976128;
  float* Bc_f   = ws + 15335424;   // 589824
  float* Bc_b   = ws + 15925248;
  float* Cc_f   = ws + 16515072;
  float* Cc_b   = ws + 17104896;
  float* y_f    = ws + 17694720;   // 2359296
  float* y_b    = ws + 20054016;
  float* aggP   = ws + 22413312;   // 1179648 (NCH=144)
  float* aggS   = ws + 23592960;   // 1179648
  float* hin    = aggP;            // in-place: P2 reads aggP[i] before writing hin[i]
  // total 24772608 floats = 94.5 MiB

  k1_conv_att<<<4608,256,0,stream>>>(x, w_att, b_att, xa);
  k2_ln_inproj<<<576,128,0,stream>>>(xa, w_in, ln_w, ln_b, xin, zs);
  k3_fused<<<dim3(NCH,2,BB),64,0,stream>>>(xin,
      cw_f,cb_f,wx_f,wdt_f,bdt_f,Al_f, cw_b,cb_b,wx_b,wdt_b,bdt_b,Al_b,
      xc_f,dl_f,Bc_f,Cc_f, xc_b,dl_b,Bc_b,Cc_b, aggP,aggS);
  p2_scan_agg<<<32,256,0,stream>>>(aggP,aggS,hin);
  p3_scan_out<<<dim3(NCH,4,BB),64,0,stream>>>(dl_f,xc_f,Bc_f,Cc_f, dl_b,xc_b,Bc_b,Cc_b,
      Al_f,D_f, Al_b,D_b, hin, y_f,y_b);
  k4_outproj<<<576,256,0,stream>>>(y_f,y_b,zs,w_out,att2);
  k5a_pool<<<144,256,0,stream>>>(x, att2, pooled);
  k5b_se_combine<<<144,256,0,stream>>>(x, att2, pooled, w_se, b_se, outbuf);
  k6_conv3x3<<<dim3(HH,2,BB),256,0,stream>>>(outbuf, w_conv, b_conv, (float*)d_out);
}